// Round 9
// baseline (897.863 us; speedup 1.0000x reference)
//
#include <hip/hip_runtime.h>
#include <hip/hip_fp16.h>
#include <math.h>

#define TPB 256
#define BSHIFT 7                 // 128 nodes per bucket
#define BNODES (1 << BSHIFT)
#define BMAX 1024                // supports n <= 131072
#define CH 4096                  // edges per bin chunk
#define STAGE_CAP 6144           // LDS edge stage per bucket

// ---------- P1: bucket histogram (LDS-privatized) ----------
__global__ __launch_bounds__(256) void hist_kernel(const int2* __restrict__ edges,
                                                   int* __restrict__ bucket_cnt,
                                                   int e, int B) {
    __shared__ int h[BMAX];
    for (int i = threadIdx.x; i < B; i += 256) h[i] = 0;
    __syncthreads();
    for (int t = blockIdx.x * 256 + threadIdx.x; t < e; t += gridDim.x * 256)
        atomicAdd(&h[edges[t].y >> BSHIFT], 1);
    __syncthreads();
    for (int i = threadIdx.x; i < B; i += 256) {
        int c = h[i];
        if (c) atomicAdd(&bucket_cnt[i], c);
    }
}

// ---------- P2: scan bucket counts ----------
__global__ __launch_bounds__(1024) void bscan_kernel(const int* __restrict__ bucket_cnt,
                                                     int* __restrict__ bucket_start,
                                                     int* __restrict__ bucket_cursor,
                                                     int* __restrict__ row_start,
                                                     int n, int e, int B) {
    __shared__ int s[BMAX];
    int t = threadIdx.x;
    s[t] = (t < B) ? bucket_cnt[t] : 0;
    __syncthreads();
    for (int off = 1; off < BMAX; off <<= 1) {
        int v = (t >= off) ? s[t - off] : 0;
        __syncthreads();
        s[t] += v;
        __syncthreads();
    }
    if (t < B) {
        int st = (t > 0) ? s[t - 1] : 0;
        bucket_start[t] = st;
        bucket_cursor[t] = st;
    }
    if (t == 0) { bucket_start[B] = e; row_start[n] = e; }
}

// ---------- P3: bin edges by bucket (block-level reservation) ----------
__global__ __launch_bounds__(256) void bin_kernel(const int2* __restrict__ edges,
                                                  int* __restrict__ bucket_cursor,
                                                  unsigned* __restrict__ ebuf,
                                                  int e, int B) {
    __shared__ int h[BMAX];
    for (long long base = (long long)blockIdx.x * CH; base < e;
         base += (long long)gridDim.x * CH) {
        int cnt = min(CH, e - (int)base);
        for (int i = threadIdx.x; i < B; i += 256) h[i] = 0;
        __syncthreads();
        for (int t = threadIdx.x; t < cnt; t += 256)
            atomicAdd(&h[edges[base + t].y >> BSHIFT], 1);
        __syncthreads();
        for (int i = threadIdx.x; i < B; i += 256) {
            int c = h[i];
            if (c) h[i] = atomicAdd(&bucket_cursor[i], c);
        }
        __syncthreads();
        for (int t = threadIdx.x; t < cnt; t += 256) {
            int2 sd = edges[base + t];
            int pos = atomicAdd(&h[sd.y >> BSHIFT], 1);
            ebuf[pos] = ((unsigned)(sd.y & (BNODES - 1)) << 17) | (unsigned)sd.x;
        }
        __syncthreads();
    }
}

// ---------- P4: per-bucket finalize: deg/dinv/row_start + csr_src ----------
__global__ __launch_bounds__(256) void finalize_kernel(const unsigned* __restrict__ ebuf,
                                                       const int* __restrict__ bucket_start,
                                                       int* __restrict__ row_start,
                                                       int* __restrict__ csr_src,
                                                       float* __restrict__ dinv, int n) {
    int b = blockIdx.x;
    int s0 = bucket_start[b], s1 = bucket_start[b + 1];
    int cnt = s1 - s0;
    int node0 = b << BSHIFT;
    int nn = min(BNODES, n - node0);
    __shared__ int ldeg[BNODES];
    __shared__ int lcur[BNODES];
    __shared__ int sc[BNODES];
    __shared__ unsigned stage[STAGE_CAP];
    int t = threadIdx.x;
    for (int i = t; i < BNODES; i += 256) ldeg[i] = 0;
    __syncthreads();
    bool uselds = (cnt <= STAGE_CAP);
    for (int tt = t; tt < cnt; tt += 256) {
        unsigned p = ebuf[s0 + tt];
        if (uselds) stage[tt] = p;
        atomicAdd(&ldeg[p >> 17], 1);
    }
    __syncthreads();
    if (t < BNODES) sc[t] = ldeg[t];
    __syncthreads();
    for (int off = 1; off < BNODES; off <<= 1) {
        int v = 0;
        if (t < BNODES && t >= off) v = sc[t - off];
        __syncthreads();
        if (t < BNODES) sc[t] += v;
        __syncthreads();
    }
    if (t < nn) {
        int excl = (t > 0) ? sc[t - 1] : 0;
        row_start[node0 + t] = s0 + excl;
        lcur[t] = s0 + excl;
        dinv[node0 + t] = rsqrtf((float)(ldeg[t] + 1));
    } else if (t < BNODES) {
        lcur[t] = 0;
    }
    __syncthreads();
    for (int tt = t; tt < cnt; tt += 256) {
        unsigned p = uselds ? stage[tt] : ebuf[s0 + tt];
        int pos = atomicAdd(&lcur[p >> 17], 1);
        csr_src[pos] = (int)(p & 0x1FFFFu);
    }
}

// ---------- transpose all weight matrices: Wt[c][k] = W[k][c] ----------
__global__ __launch_bounds__(256) void transposeW_kernel(
    const float* __restrict__ W1, const float* __restrict__ W2,
    const float* __restrict__ W3, const float* __restrict__ W4,
    const float* __restrict__ Wl1, float* __restrict__ wt) {
    int idx = blockIdx.x * 256 + threadIdx.x;
    if (idx < 2048) {                       // W1: 32x64 -> wt[64][32]
        int c = idx >> 5, k = idx & 31;
        wt[idx] = W1[k * 64 + c];
    } else if (idx < 2048 + 4 * 6144) {     // W2..W4,Wl1: 96x64 -> [64][96]
        int j = idx - 2048;
        int m = j / 6144, r = j - m * 6144;
        int c = r / 96, k = r - c * 96;
        const float* src = (m == 0) ? W2 : (m == 1) ? W3 : (m == 2) ? W4 : Wl1;
        wt[idx] = src[k * 64 + c];
    }
}

// ---------- channel-split register GEMM ------------------------------------
// 256 threads = 4 waves share 64 nodes; wave wq computes channels
// [wq*16, wq*16+16). Input row in VGPRs; W via uniform scalar loads; direct
// vector stores (no LDS). 4x the waves of the lane=node design -> latency
// hiding; epilogue bank conflicts eliminated.
// MODE 0: out fp16 Tsh row = (row @ W) * dinv[i]
// MODE 1: out fp32       = relu(row @ W + bias)  (in-place on h: __syncthreads
//         after register loads orders all reads before any writes)
template <int FIN, int MODE>
__global__ __launch_bounds__(256) void gemm_node_t(
    const float* __restrict__ x, const float* __restrict__ h,
    const float* __restrict__ Wt, const float* __restrict__ bias,
    const float* __restrict__ dinv, void* __restrict__ out, int n) {
    int lane = threadIdx.x & 63;
    int wq = threadIdx.x >> 6;          // 0..3 -> channel group
    int node0 = blockIdx.x << 6;
    int i = node0 + lane;
    int ic = min(i, n - 1);
    float xr[FIN];
    const float4* xp = (const float4*)(x + (size_t)ic * 32);
#pragma unroll
    for (int q = 0; q < 8; q++) {
        float4 v = xp[q];
        xr[q * 4] = v.x; xr[q * 4 + 1] = v.y; xr[q * 4 + 2] = v.z; xr[q * 4 + 3] = v.w;
    }
    if (FIN == 96) {
        const float4* hp = (const float4*)(h + (size_t)ic * 64);
#pragma unroll
        for (int q = 0; q < 16; q++) {
            float4 v = hp[q];
            xr[32 + q * 4] = v.x; xr[32 + q * 4 + 1] = v.y;
            xr[32 + q * 4 + 2] = v.z; xr[32 + q * 4 + 3] = v.w;
        }
    }
    if (MODE == 1) __syncthreads();     // in-place safety: all reads before writes
    float scale = (MODE == 0) ? dinv[ic] : 0.f;
    float res[16];
#pragma unroll
    for (int cc = 0; cc < 16; cc++) {
        const float* wc = Wt + (wq * 16 + cc) * FIN;   // wave-uniform -> s_loads
        float a0 = 0.f, a1 = 0.f;
#pragma unroll
        for (int k = 0; k < FIN; k += 2) {
            a0 = fmaf(xr[k], wc[k], a0);
            a1 = fmaf(xr[k + 1], wc[k + 1], a1);
        }
        res[cc] = a0 + a1;
    }
    if (i >= n) return;
    if (MODE == 0) {
        union { unsigned short us[16]; uint4 v[2]; } u;
#pragma unroll
        for (int cc = 0; cc < 16; cc++)
            u.us[cc] = __half_as_ushort(__float2half(res[cc] * scale));
        uint4* dst = (uint4*)((unsigned short*)out + (size_t)i * 64 + wq * 16);
        dst[0] = u.v[0];
        dst[1] = u.v[1];
    } else {
        const float* bp = bias + wq * 16;
        float4* dst = (float4*)((float*)out + (size_t)i * 64 + wq * 16);
#pragma unroll
        for (int t4 = 0; t4 < 4; t4++) {
            float4 o;
            o.x = fmaxf(res[t4 * 4 + 0] + bp[t4 * 4 + 0], 0.f);
            o.y = fmaxf(res[t4 * 4 + 1] + bp[t4 * 4 + 1], 0.f);
            o.z = fmaxf(res[t4 * 4 + 2] + bp[t4 * 4 + 2], 0.f);
            o.w = fmaxf(res[t4 * 4 + 3] + bp[t4 * 4 + 3], 0.f);
            dst[t4] = o;
        }
    }
}

// ---------- pull aggregation over fp16 messages ----------
// 8 lanes/node, 16 B (8 halves) per lane; fp32 accumulate; unroll 2 with
// two independent accumulator sets. 32 nodes per 256-thread block.
__device__ __forceinline__ void acc8(const uint4 v, float* a) {
    float2 f;
    f = __half22float2(*(const __half2*)&v.x); a[0] += f.x; a[1] += f.y;
    f = __half22float2(*(const __half2*)&v.y); a[2] += f.x; a[3] += f.y;
    f = __half22float2(*(const __half2*)&v.z); a[4] += f.x; a[5] += f.y;
    f = __half22float2(*(const __half2*)&v.w); a[6] += f.x; a[7] += f.y;
}

__global__ __launch_bounds__(256) void aggregate_h(
    const uint4* __restrict__ Tsh4, const int* __restrict__ row_start,
    const int* __restrict__ csr_src, const float* __restrict__ dinv,
    const float* __restrict__ bias, float* __restrict__ hout, int n) {
    int i = blockIdx.x * 32 + (threadIdx.x >> 3);
    if (i >= n) return;
    int q = threadIdx.x & 7;           // channels q*8 .. q*8+7
    float accA[8], accB[8];
#pragma unroll
    for (int k = 0; k < 8; k++) accB[k] = 0.f;
    {   // self loop (Tsh already * dinv[i])
        uint4 sv = Tsh4[(size_t)i * 8 + q];
        float2 f;
        f = __half22float2(*(const __half2*)&sv.x); accA[0] = f.x; accA[1] = f.y;
        f = __half22float2(*(const __half2*)&sv.y); accA[2] = f.x; accA[3] = f.y;
        f = __half22float2(*(const __half2*)&sv.z); accA[4] = f.x; accA[5] = f.y;
        f = __half22float2(*(const __half2*)&sv.w); accA[6] = f.x; accA[7] = f.y;
    }
    int s0 = row_start[i], s1 = row_start[i + 1];
    int j = s0;
    for (; j + 2 <= s1; j += 2) {
        int sa = csr_src[j], sb = csr_src[j + 1];
        uint4 va = Tsh4[(size_t)sa * 8 + q];
        uint4 vb = Tsh4[(size_t)sb * 8 + q];
        acc8(va, accA);
        acc8(vb, accB);
    }
    if (j < s1) {
        int sa = csr_src[j];
        acc8(Tsh4[(size_t)sa * 8 + q], accA);
    }
    float di = dinv[i];
    const float4* bp = (const float4*)(bias + q * 8);
    float4 b0 = bp[0], b1 = bp[1];
    float4 o0, o1;
    o0.x = fmaxf((accA[0] + accB[0]) * di + b0.x, 0.f);
    o0.y = fmaxf((accA[1] + accB[1]) * di + b0.y, 0.f);
    o0.z = fmaxf((accA[2] + accB[2]) * di + b0.z, 0.f);
    o0.w = fmaxf((accA[3] + accB[3]) * di + b0.w, 0.f);
    o1.x = fmaxf((accA[4] + accB[4]) * di + b1.x, 0.f);
    o1.y = fmaxf((accA[5] + accB[5]) * di + b1.y, 0.f);
    o1.z = fmaxf((accA[6] + accB[6]) * di + b1.z, 0.f);
    o1.w = fmaxf((accA[7] + accB[7]) * di + b1.w, 0.f);
    float4* op = (float4*)(hout + (size_t)i * 64 + q * 8);
    op[0] = o0;
    op[1] = o1;
}

// ---------- final head: sigmoid(concat(x,h5) @ Wl2 + bl2) ----------
__global__ __launch_bounds__(256) void final_kernel(
    const float* __restrict__ x, const float* __restrict__ h5,
    const float* __restrict__ Wl2, const float* __restrict__ bl2,
    float* __restrict__ out, int n) {
    int i = blockIdx.x * TPB + threadIdx.x;
    if (i >= n) return;
    float acc = bl2[0];
#pragma unroll
    for (int k = 0; k < 32; k++) acc = fmaf(x[(size_t)i * 32 + k], Wl2[k], acc);
#pragma unroll
    for (int k = 0; k < 64; k++) acc = fmaf(h5[(size_t)i * 64 + k], Wl2[32 + k], acc);
    out[i] = 1.f / (1.f + expf(-acc));
}

extern "C" void kernel_launch(void* const* d_in, const int* in_sizes, int n_in,
                              void* d_out, int out_size, void* d_ws, size_t ws_size,
                              hipStream_t stream) {
    const float* x   = (const float*)d_in[0];
    const int*   edg = (const int*)d_in[1];
    const float* W1  = (const float*)d_in[2];
    const float* b1  = (const float*)d_in[3];
    const float* W2  = (const float*)d_in[4];
    const float* b2  = (const float*)d_in[5];
    const float* W3  = (const float*)d_in[6];
    const float* b3  = (const float*)d_in[7];
    const float* W4  = (const float*)d_in[8];
    const float* b4  = (const float*)d_in[9];
    const float* Wl1 = (const float*)d_in[10];
    const float* bl1 = (const float*)d_in[11];
    const float* Wl2 = (const float*)d_in[12];
    const float* bl2 = (const float*)d_in[13];
    int n = in_sizes[0] / 32;
    int e = in_sizes[1] / 2;
    int B = (n + BNODES - 1) >> BSHIFT;

    char* ws = (char*)d_ws;
    size_t off = 0;
    auto take = [&](size_t bytes) {
        char* p = ws + off;
        off = (off + bytes + 255) & ~(size_t)255;
        return p;
    };
    int*   bucket_cnt    = (int*)take((size_t)B * 4);
    int*   bucket_start  = (int*)take((size_t)(B + 1) * 4);
    int*   bucket_cursor = (int*)take((size_t)B * 4);
    int*   row_start     = (int*)take((size_t)(n + 1) * 4);
    int*   csr_src       = (int*)take((size_t)e * 4);
    float* dinv          = (float*)take((size_t)n * 4);
    float* wt            = (float*)take((size_t)26624 * 4);
    unsigned* Tsh        = (unsigned*)take((size_t)n * 64 * 2);  // fp16 messages
    float* hbuf          = (float*)take((size_t)n * 64 * 4);
    unsigned* ebuf = (unsigned*)Tsh;  // alias (e*4 == n*128 here); consumed before gemm1
    float* wt1  = wt;
    float* wt2  = wt + 2048;
    float* wt3  = wt + 2048 + 6144;
    float* wt4  = wt + 2048 + 2 * 6144;
    float* wtl1 = wt + 2048 + 3 * 6144;

    hipMemsetAsync(bucket_cnt, 0, (size_t)B * 4, stream);

    int nb = (n + TPB - 1) / TPB;
    int nchunks = (e + CH - 1) / CH;
    hist_kernel<<<512, 256, 0, stream>>>((const int2*)edg, bucket_cnt, e, B);
    bscan_kernel<<<1, 1024, 0, stream>>>(bucket_cnt, bucket_start, bucket_cursor,
                                         row_start, n, e, B);
    bin_kernel<<<nchunks, 256, 0, stream>>>((const int2*)edg, bucket_cursor, ebuf, e, B);
    finalize_kernel<<<B, 256, 0, stream>>>(ebuf, bucket_start, row_start, csr_src, dinv, n);
    transposeW_kernel<<<104, 256, 0, stream>>>(W1, W2, W3, W4, Wl1, wt);

    int gb = (n + 63) / 64;   // gemm blocks: 64 nodes, 256 threads (4 waves x 16 ch)
    int ab = (n + 31) / 32;   // aggregate blocks: 32 nodes each (8 lanes/node)

    gemm_node_t<32, 0><<<gb, TPB, 0, stream>>>(x, nullptr, wt1, nullptr, dinv, Tsh, n);
    aggregate_h<<<ab, TPB, 0, stream>>>((const uint4*)Tsh, row_start, csr_src, dinv, b1, hbuf, n);
    gemm_node_t<96, 0><<<gb, TPB, 0, stream>>>(x, hbuf, wt2, nullptr, dinv, Tsh, n);
    aggregate_h<<<ab, TPB, 0, stream>>>((const uint4*)Tsh, row_start, csr_src, dinv, b2, hbuf, n);
    gemm_node_t<96, 0><<<gb, TPB, 0, stream>>>(x, hbuf, wt3, nullptr, dinv, Tsh, n);
    aggregate_h<<<ab, TPB, 0, stream>>>((const uint4*)Tsh, row_start, csr_src, dinv, b3, hbuf, n);
    gemm_node_t<96, 0><<<gb, TPB, 0, stream>>>(x, hbuf, wt4, nullptr, dinv, Tsh, n);
    aggregate_h<<<ab, TPB, 0, stream>>>((const uint4*)Tsh, row_start, csr_src, dinv, b4, hbuf, n);
    // lin1 in-place: hbuf = relu(concat(x,hbuf) @ Wl1 + bl1)
    gemm_node_t<96, 1><<<gb, TPB, 0, stream>>>(x, hbuf, wtl1, bl1, dinv, hbuf, n);
    final_kernel<<<nb, TPB, 0, stream>>>(x, hbuf, Wl2, bl2, (float*)d_out, n);
}

// Round 10
// 569.820 us; speedup vs baseline: 1.5757x; 1.5757x over previous
//
#include <hip/hip_runtime.h>
#include <hip/hip_fp16.h>
#include <math.h>

#define TPB 256
#define BSHIFT 7                 // 128 nodes per bucket
#define BNODES (1 << BSHIFT)
#define BMAX 1024                // supports n <= 131072
#define CH 4096                  // edges per bin chunk
#define STAGE_CAP 6144           // LDS edge stage per bucket

// ---------- P1: bucket histogram (LDS-privatized) ----------
__global__ __launch_bounds__(256) void hist_kernel(const int2* __restrict__ edges,
                                                   int* __restrict__ bucket_cnt,
                                                   int e, int B) {
    __shared__ int h[BMAX];
    for (int i = threadIdx.x; i < B; i += 256) h[i] = 0;
    __syncthreads();
    for (int t = blockIdx.x * 256 + threadIdx.x; t < e; t += gridDim.x * 256)
        atomicAdd(&h[edges[t].y >> BSHIFT], 1);
    __syncthreads();
    for (int i = threadIdx.x; i < B; i += 256) {
        int c = h[i];
        if (c) atomicAdd(&bucket_cnt[i], c);
    }
}

// ---------- P2: scan bucket counts ----------
__global__ __launch_bounds__(1024) void bscan_kernel(const int* __restrict__ bucket_cnt,
                                                     int* __restrict__ bucket_start,
                                                     int* __restrict__ bucket_cursor,
                                                     int* __restrict__ row_start,
                                                     int n, int e, int B) {
    __shared__ int s[BMAX];
    int t = threadIdx.x;
    s[t] = (t < B) ? bucket_cnt[t] : 0;
    __syncthreads();
    for (int off = 1; off < BMAX; off <<= 1) {
        int v = (t >= off) ? s[t - off] : 0;
        __syncthreads();
        s[t] += v;
        __syncthreads();
    }
    if (t < B) {
        int st = (t > 0) ? s[t - 1] : 0;
        bucket_start[t] = st;
        bucket_cursor[t] = st;
    }
    if (t == 0) { bucket_start[B] = e; row_start[n] = e; }
}

// ---------- P3: bin edges by bucket (block-level reservation) ----------
__global__ __launch_bounds__(256) void bin_kernel(const int2* __restrict__ edges,
                                                  int* __restrict__ bucket_cursor,
                                                  unsigned* __restrict__ ebuf,
                                                  int e, int B) {
    __shared__ int h[BMAX];
    for (long long base = (long long)blockIdx.x * CH; base < e;
         base += (long long)gridDim.x * CH) {
        int cnt = min(CH, e - (int)base);
        for (int i = threadIdx.x; i < B; i += 256) h[i] = 0;
        __syncthreads();
        for (int t = threadIdx.x; t < cnt; t += 256)
            atomicAdd(&h[edges[base + t].y >> BSHIFT], 1);
        __syncthreads();
        for (int i = threadIdx.x; i < B; i += 256) {
            int c = h[i];
            if (c) h[i] = atomicAdd(&bucket_cursor[i], c);
        }
        __syncthreads();
        for (int t = threadIdx.x; t < cnt; t += 256) {
            int2 sd = edges[base + t];
            int pos = atomicAdd(&h[sd.y >> BSHIFT], 1);
            ebuf[pos] = ((unsigned)(sd.y & (BNODES - 1)) << 17) | (unsigned)sd.x;
        }
        __syncthreads();
    }
}

// ---------- P4: per-bucket finalize: deg/dinv/row_start + csr_src ----------
__global__ __launch_bounds__(256) void finalize_kernel(const unsigned* __restrict__ ebuf,
                                                       const int* __restrict__ bucket_start,
                                                       int* __restrict__ row_start,
                                                       int* __restrict__ csr_src,
                                                       float* __restrict__ dinv, int n) {
    int b = blockIdx.x;
    int s0 = bucket_start[b], s1 = bucket_start[b + 1];
    int cnt = s1 - s0;
    int node0 = b << BSHIFT;
    int nn = min(BNODES, n - node0);
    __shared__ int ldeg[BNODES];
    __shared__ int lcur[BNODES];
    __shared__ int sc[BNODES];
    __shared__ unsigned stage[STAGE_CAP];
    int t = threadIdx.x;
    for (int i = t; i < BNODES; i += 256) ldeg[i] = 0;
    __syncthreads();
    bool uselds = (cnt <= STAGE_CAP);
    for (int tt = t; tt < cnt; tt += 256) {
        unsigned p = ebuf[s0 + tt];
        if (uselds) stage[tt] = p;
        atomicAdd(&ldeg[p >> 17], 1);
    }
    __syncthreads();
    if (t < BNODES) sc[t] = ldeg[t];
    __syncthreads();
    for (int off = 1; off < BNODES; off <<= 1) {
        int v = 0;
        if (t < BNODES && t >= off) v = sc[t - off];
        __syncthreads();
        if (t < BNODES) sc[t] += v;
        __syncthreads();
    }
    if (t < nn) {
        int excl = (t > 0) ? sc[t - 1] : 0;
        row_start[node0 + t] = s0 + excl;
        lcur[t] = s0 + excl;
        dinv[node0 + t] = rsqrtf((float)(ldeg[t] + 1));
    } else if (t < BNODES) {
        lcur[t] = 0;
    }
    __syncthreads();
    for (int tt = t; tt < cnt; tt += 256) {
        unsigned p = uselds ? stage[tt] : ebuf[s0 + tt];
        int pos = atomicAdd(&lcur[p >> 17], 1);
        csr_src[pos] = (int)(p & 0x1FFFFu);
    }
}

// ---------- k-outer channel-split GEMM -------------------------------------
// 256 threads = 4 waves share 64 nodes; wave wq computes channels
// [wq*16, wq*16+16). K-outer loop: input row STREAMS one float4 at a time
// (no large live register array -> compiler cannot rematerialize; ~30 VGPR).
// W in ORIGINAL [k][64] layout; per k the wave's 16 channels are contiguous
// floats at a wave-uniform address (wq via readfirstlane) -> s_load, no VALU.
// MODE 0: out fp16 Tsh row = (row @ W) * dinv[i]
// MODE 1: out fp32 = relu(row @ W + bias); in-place on h is safe: barrier
//         after the streaming loop (all reads consumed) before any store.
template <int FIN, int MODE>
__device__ __forceinline__ void accum4(const float4 v, const float* __restrict__ wk,
                                       float* __restrict__ res) {
    // wk points at W[k][wq*16] for the float4's first k; rows stride 64.
#pragma unroll
    for (int cc = 0; cc < 16; cc++) res[cc] = fmaf(v.x, wk[cc], res[cc]);
#pragma unroll
    for (int cc = 0; cc < 16; cc++) res[cc] = fmaf(v.y, wk[64 + cc], res[cc]);
#pragma unroll
    for (int cc = 0; cc < 16; cc++) res[cc] = fmaf(v.z, wk[128 + cc], res[cc]);
#pragma unroll
    for (int cc = 0; cc < 16; cc++) res[cc] = fmaf(v.w, wk[192 + cc], res[cc]);
}

template <int FIN, int MODE>
__global__ __launch_bounds__(256) void gemm_node_k(
    const float* __restrict__ x, const float* __restrict__ h,
    const float* __restrict__ W, const float* __restrict__ bias,
    const float* __restrict__ dinv, void* __restrict__ out, int n) {
    int lane = threadIdx.x & 63;
    int wq = __builtin_amdgcn_readfirstlane(threadIdx.x >> 6);  // 0..3, SGPR
    int node0 = blockIdx.x << 6;
    int i = node0 + lane;
    int ic = min(i, n - 1);
    float res[16];
#pragma unroll
    for (int cc = 0; cc < 16; cc++) res[cc] = 0.f;
    const float* Wq = W + wq * 16;               // wave-uniform base
    const float4* xp = (const float4*)(x + (size_t)ic * 32);
#pragma unroll
    for (int q = 0; q < 8; q++)
        accum4<FIN, MODE>(xp[q], Wq + (size_t)(q * 4) * 64, res);
    if (FIN == 96) {
        const float4* hp = (const float4*)(h + (size_t)ic * 64);
#pragma unroll
        for (int q = 0; q < 16; q++)
            accum4<FIN, MODE>(hp[q], Wq + (size_t)(32 + q * 4) * 64, res);
    }
    if (MODE == 1) __syncthreads();   // in-place safety: all reads consumed
    if (i >= n) return;
    if (MODE == 0) {
        float scale = dinv[ic];
        union { unsigned short us[16]; uint4 v[2]; } u;
#pragma unroll
        for (int cc = 0; cc < 16; cc++)
            u.us[cc] = __half_as_ushort(__float2half(res[cc] * scale));
        uint4* dst = (uint4*)((unsigned short*)out + (size_t)i * 64 + wq * 16);
        dst[0] = u.v[0];
        dst[1] = u.v[1];
    } else {
        const float* bp = bias + wq * 16;
        float4* dst = (float4*)((float*)out + (size_t)i * 64 + wq * 16);
#pragma unroll
        for (int t4 = 0; t4 < 4; t4++) {
            float4 o;
            o.x = fmaxf(res[t4 * 4 + 0] + bp[t4 * 4 + 0], 0.f);
            o.y = fmaxf(res[t4 * 4 + 1] + bp[t4 * 4 + 1], 0.f);
            o.z = fmaxf(res[t4 * 4 + 2] + bp[t4 * 4 + 2], 0.f);
            o.w = fmaxf(res[t4 * 4 + 3] + bp[t4 * 4 + 3], 0.f);
            dst[t4] = o;
        }
    }
}

// ---------- pull aggregation over fp16 messages ----------
// 8 lanes/node, 16 B (8 halves) per lane; fp32 accumulate; unroll 2 with
// two independent accumulator sets. 32 nodes per 256-thread block.
__device__ __forceinline__ void acc8(const uint4 v, float* a) {
    float2 f;
    f = __half22float2(*(const __half2*)&v.x); a[0] += f.x; a[1] += f.y;
    f = __half22float2(*(const __half2*)&v.y); a[2] += f.x; a[3] += f.y;
    f = __half22float2(*(const __half2*)&v.z); a[4] += f.x; a[5] += f.y;
    f = __half22float2(*(const __half2*)&v.w); a[6] += f.x; a[7] += f.y;
}

__global__ __launch_bounds__(256) void aggregate_h(
    const uint4* __restrict__ Tsh4, const int* __restrict__ row_start,
    const int* __restrict__ csr_src, const float* __restrict__ dinv,
    const float* __restrict__ bias, float* __restrict__ hout, int n) {
    int i = blockIdx.x * 32 + (threadIdx.x >> 3);
    if (i >= n) return;
    int q = threadIdx.x & 7;           // channels q*8 .. q*8+7
    float accA[8], accB[8];
#pragma unroll
    for (int k = 0; k < 8; k++) accB[k] = 0.f;
    {   // self loop (Tsh already * dinv[i])
        uint4 sv = Tsh4[(size_t)i * 8 + q];
        float2 f;
        f = __half22float2(*(const __half2*)&sv.x); accA[0] = f.x; accA[1] = f.y;
        f = __half22float2(*(const __half2*)&sv.y); accA[2] = f.x; accA[3] = f.y;
        f = __half22float2(*(const __half2*)&sv.z); accA[4] = f.x; accA[5] = f.y;
        f = __half22float2(*(const __half2*)&sv.w); accA[6] = f.x; accA[7] = f.y;
    }
    int s0 = row_start[i], s1 = row_start[i + 1];
    int j = s0;
    for (; j + 2 <= s1; j += 2) {
        int sa = csr_src[j], sb = csr_src[j + 1];
        uint4 va = Tsh4[(size_t)sa * 8 + q];
        uint4 vb = Tsh4[(size_t)sb * 8 + q];
        acc8(va, accA);
        acc8(vb, accB);
    }
    if (j < s1) {
        int sa = csr_src[j];
        acc8(Tsh4[(size_t)sa * 8 + q], accA);
    }
    float di = dinv[i];
    const float4* bp = (const float4*)(bias + q * 8);
    float4 b0 = bp[0], b1 = bp[1];
    float4 o0, o1;
    o0.x = fmaxf((accA[0] + accB[0]) * di + b0.x, 0.f);
    o0.y = fmaxf((accA[1] + accB[1]) * di + b0.y, 0.f);
    o0.z = fmaxf((accA[2] + accB[2]) * di + b0.z, 0.f);
    o0.w = fmaxf((accA[3] + accB[3]) * di + b0.w, 0.f);
    o1.x = fmaxf((accA[4] + accB[4]) * di + b1.x, 0.f);
    o1.y = fmaxf((accA[5] + accB[5]) * di + b1.y, 0.f);
    o1.z = fmaxf((accA[6] + accB[6]) * di + b1.z, 0.f);
    o1.w = fmaxf((accA[7] + accB[7]) * di + b1.w, 0.f);
    float4* op = (float4*)(hout + (size_t)i * 64 + q * 8);
    op[0] = o0;
    op[1] = o1;
}

// ---------- final head: sigmoid(concat(x,h5) @ Wl2 + bl2) ----------
__global__ __launch_bounds__(256) void final_kernel(
    const float* __restrict__ x, const float* __restrict__ h5,
    const float* __restrict__ Wl2, const float* __restrict__ bl2,
    float* __restrict__ out, int n) {
    int i = blockIdx.x * TPB + threadIdx.x;
    if (i >= n) return;
    float acc = bl2[0];
#pragma unroll
    for (int k = 0; k < 32; k++) acc = fmaf(x[(size_t)i * 32 + k], Wl2[k], acc);
#pragma unroll
    for (int k = 0; k < 64; k++) acc = fmaf(h5[(size_t)i * 64 + k], Wl2[32 + k], acc);
    out[i] = 1.f / (1.f + expf(-acc));
}

extern "C" void kernel_launch(void* const* d_in, const int* in_sizes, int n_in,
                              void* d_out, int out_size, void* d_ws, size_t ws_size,
                              hipStream_t stream) {
    const float* x   = (const float*)d_in[0];
    const int*   edg = (const int*)d_in[1];
    const float* W1  = (const float*)d_in[2];
    const float* b1  = (const float*)d_in[3];
    const float* W2  = (const float*)d_in[4];
    const float* b2  = (const float*)d_in[5];
    const float* W3  = (const float*)d_in[6];
    const float* b3  = (const float*)d_in[7];
    const float* W4  = (const float*)d_in[8];
    const float* b4  = (const float*)d_in[9];
    const float* Wl1 = (const float*)d_in[10];
    const float* bl1 = (const float*)d_in[11];
    const float* Wl2 = (const float*)d_in[12];
    const float* bl2 = (const float*)d_in[13];
    int n = in_sizes[0] / 32;
    int e = in_sizes[1] / 2;
    int B = (n + BNODES - 1) >> BSHIFT;

    char* ws = (char*)d_ws;
    size_t off = 0;
    auto take = [&](size_t bytes) {
        char* p = ws + off;
        off = (off + bytes + 255) & ~(size_t)255;
        return p;
    };
    int*   bucket_cnt    = (int*)take((size_t)B * 4);
    int*   bucket_start  = (int*)take((size_t)(B + 1) * 4);
    int*   bucket_cursor = (int*)take((size_t)B * 4);
    int*   row_start     = (int*)take((size_t)(n + 1) * 4);
    int*   csr_src       = (int*)take((size_t)e * 4);
    float* dinv          = (float*)take((size_t)n * 4);
    unsigned* Tsh        = (unsigned*)take((size_t)n * 64 * 2);  // fp16 messages
    float* hbuf          = (float*)take((size_t)n * 64 * 4);
    unsigned* ebuf = (unsigned*)Tsh;  // alias (e*4 == n*128 here); consumed before gemm1

    hipMemsetAsync(bucket_cnt, 0, (size_t)B * 4, stream);

    int nb = (n + TPB - 1) / TPB;
    int nchunks = (e + CH - 1) / CH;
    hist_kernel<<<512, 256, 0, stream>>>((const int2*)edg, bucket_cnt, e, B);
    bscan_kernel<<<1, 1024, 0, stream>>>(bucket_cnt, bucket_start, bucket_cursor,
                                         row_start, n, e, B);
    bin_kernel<<<nchunks, 256, 0, stream>>>((const int2*)edg, bucket_cursor, ebuf, e, B);
    finalize_kernel<<<B, 256, 0, stream>>>(ebuf, bucket_start, row_start, csr_src, dinv, n);

    int gb = (n + 63) / 64;   // gemm blocks: 64 nodes, 256 threads (4 waves x 16 ch)
    int ab = (n + 31) / 32;   // aggregate blocks: 32 nodes each (8 lanes/node)

    gemm_node_k<32, 0><<<gb, TPB, 0, stream>>>(x, nullptr, W1, nullptr, dinv, Tsh, n);
    aggregate_h<<<ab, TPB, 0, stream>>>((const uint4*)Tsh, row_start, csr_src, dinv, b1, hbuf, n);
    gemm_node_k<96, 0><<<gb, TPB, 0, stream>>>(x, hbuf, W2, nullptr, dinv, Tsh, n);
    aggregate_h<<<ab, TPB, 0, stream>>>((const uint4*)Tsh, row_start, csr_src, dinv, b2, hbuf, n);
    gemm_node_k<96, 0><<<gb, TPB, 0, stream>>>(x, hbuf, W3, nullptr, dinv, Tsh, n);
    aggregate_h<<<ab, TPB, 0, stream>>>((const uint4*)Tsh, row_start, csr_src, dinv, b3, hbuf, n);
    gemm_node_k<96, 0><<<gb, TPB, 0, stream>>>(x, hbuf, W4, nullptr, dinv, Tsh, n);
    aggregate_h<<<ab, TPB, 0, stream>>>((const uint4*)Tsh, row_start, csr_src, dinv, b4, hbuf, n);
    // lin1 in-place: hbuf = relu(concat(x,hbuf) @ Wl1 + bl1)
    gemm_node_k<96, 1><<<gb, TPB, 0, stream>>>(x, hbuf, Wl1, bl1, dinv, hbuf, n);
    final_kernel<<<nb, TPB, 0, stream>>>(x, hbuf, Wl2, bl2, (float*)d_out, n);
}

// Round 14
// 558.284 us; speedup vs baseline: 1.6083x; 1.0207x over previous
//
#include <hip/hip_runtime.h>
#include <hip/hip_fp16.h>
#include <math.h>

#define TPB 256
#define BSHIFT 7                 // 128 nodes per bucket
#define BNODES (1 << BSHIFT)
#define BMAX 1024                // supports n <= 131072
#define CH 4096                  // edges per bin chunk
#define SPAN (4 * CH)            // contiguous edges per bin block (XCD locality)
#define STAGE_CAP 6144           // LDS edge stage per bucket

// ---------- P1: bucket histogram (LDS-privatized) ----------
__global__ __launch_bounds__(256) void hist_kernel(const int2* __restrict__ edges,
                                                   int* __restrict__ bucket_cnt,
                                                   int e, int B) {
    __shared__ int h[BMAX];
    for (int i = threadIdx.x; i < B; i += 256) h[i] = 0;
    __syncthreads();
    for (int t = blockIdx.x * 256 + threadIdx.x; t < e; t += gridDim.x * 256)
        atomicAdd(&h[edges[t].y >> BSHIFT], 1);
    __syncthreads();
    for (int i = threadIdx.x; i < B; i += 256) {
        int c = h[i];
        if (c) atomicAdd(&bucket_cnt[i], c);
    }
}

// ---------- P2: scan bucket counts ----------
__global__ __launch_bounds__(1024) void bscan_kernel(const int* __restrict__ bucket_cnt,
                                                     int* __restrict__ bucket_start,
                                                     int* __restrict__ bucket_cursor,
                                                     int* __restrict__ row_start,
                                                     int n, int e, int B) {
    __shared__ int s[BMAX];
    int t = threadIdx.x;
    s[t] = (t < B) ? bucket_cnt[t] : 0;
    __syncthreads();
    for (int off = 1; off < BMAX; off <<= 1) {
        int v = (t >= off) ? s[t - off] : 0;
        __syncthreads();
        s[t] += v;
        __syncthreads();
    }
    if (t < B) {
        int st = (t > 0) ? s[t - 1] : 0;
        bucket_start[t] = st;
        bucket_cursor[t] = st;
    }
    if (t == 0) { bucket_start[B] = e; row_start[n] = e; }
}

// ---------- P3: bin edges by bucket (block-contiguous spans) ----------
// Each block owns a CONTIGUOUS span of SPAN edges (4 chunks). A bucket's
// consecutively-reserved positions are thus written by one block -> one XCD
// L2 -> cache lines fill before write-back (fixes 7.6x write amplification
// seen with interleaved chunks: lines ping-ponged across non-coherent L2s).
__global__ __launch_bounds__(256) void bin_kernel(const int2* __restrict__ edges,
                                                  int* __restrict__ bucket_cursor,
                                                  unsigned* __restrict__ ebuf,
                                                  int e, int B) {
    __shared__ int h[BMAX];
    long long start = (long long)blockIdx.x * SPAN;
    long long endS = start + SPAN < (long long)e ? start + SPAN : (long long)e;
    for (long long base = start; base < endS; base += CH) {
        int cnt = (int)((endS - base) < CH ? (endS - base) : CH);
        for (int i = threadIdx.x; i < B; i += 256) h[i] = 0;
        __syncthreads();
        for (int t = threadIdx.x; t < cnt; t += 256)
            atomicAdd(&h[edges[base + t].y >> BSHIFT], 1);
        __syncthreads();
        for (int i = threadIdx.x; i < B; i += 256) {
            int c = h[i];
            if (c) h[i] = atomicAdd(&bucket_cursor[i], c);
        }
        __syncthreads();
        for (int t = threadIdx.x; t < cnt; t += 256) {
            int2 sd = edges[base + t];
            int pos = atomicAdd(&h[sd.y >> BSHIFT], 1);
            ebuf[pos] = ((unsigned)(sd.y & (BNODES - 1)) << 17) | (unsigned)sd.x;
        }
        __syncthreads();
    }
}

// ---------- P4: per-bucket finalize: deg/dinv/row_start + csr_src ----------
__global__ __launch_bounds__(256) void finalize_kernel(const unsigned* __restrict__ ebuf,
                                                       const int* __restrict__ bucket_start,
                                                       int* __restrict__ row_start,
                                                       int* __restrict__ csr_src,
                                                       float* __restrict__ dinv, int n) {
    int b = blockIdx.x;
    int s0 = bucket_start[b], s1 = bucket_start[b + 1];
    int cnt = s1 - s0;
    int node0 = b << BSHIFT;
    int nn = min(BNODES, n - node0);
    __shared__ int ldeg[BNODES];
    __shared__ int lcur[BNODES];
    __shared__ int sc[BNODES];
    __shared__ unsigned stage[STAGE_CAP];
    int t = threadIdx.x;
    for (int i = t; i < BNODES; i += 256) ldeg[i] = 0;
    __syncthreads();
    bool uselds = (cnt <= STAGE_CAP);
    for (int tt = t; tt < cnt; tt += 256) {
        unsigned p = ebuf[s0 + tt];
        if (uselds) stage[tt] = p;
        atomicAdd(&ldeg[p >> 17], 1);
    }
    __syncthreads();
    if (t < BNODES) sc[t] = ldeg[t];
    __syncthreads();
    for (int off = 1; off < BNODES; off <<= 1) {
        int v = 0;
        if (t < BNODES && t >= off) v = sc[t - off];
        __syncthreads();
        if (t < BNODES) sc[t] += v;
        __syncthreads();
    }
    if (t < nn) {
        int excl = (t > 0) ? sc[t - 1] : 0;
        row_start[node0 + t] = s0 + excl;
        lcur[t] = s0 + excl;
        dinv[node0 + t] = rsqrtf((float)(ldeg[t] + 1));
    } else if (t < BNODES) {
        lcur[t] = 0;
    }
    __syncthreads();
    for (int tt = t; tt < cnt; tt += 256) {
        unsigned p = uselds ? stage[tt] : ebuf[s0 + tt];
        int pos = atomicAdd(&lcur[p >> 17], 1);
        csr_src[pos] = (int)(p & 0x1FFFFu);
    }
}

// ---------- k-outer channel-split GEMM -------------------------------------
template <int FIN, int MODE>
__device__ __forceinline__ void accum4(const float4 v, const float* __restrict__ wk,
                                       float* __restrict__ res) {
#pragma unroll
    for (int cc = 0; cc < 16; cc++) res[cc] = fmaf(v.x, wk[cc], res[cc]);
#pragma unroll
    for (int cc = 0; cc < 16; cc++) res[cc] = fmaf(v.y, wk[64 + cc], res[cc]);
#pragma unroll
    for (int cc = 0; cc < 16; cc++) res[cc] = fmaf(v.z, wk[128 + cc], res[cc]);
#pragma unroll
    for (int cc = 0; cc < 16; cc++) res[cc] = fmaf(v.w, wk[192 + cc], res[cc]);
}

template <int FIN, int MODE>
__global__ __launch_bounds__(256) void gemm_node_k(
    const float* __restrict__ x, const float* __restrict__ h,
    const float* __restrict__ W, const float* __restrict__ bias,
    const float* __restrict__ dinv, void* __restrict__ out, int n) {
    int lane = threadIdx.x & 63;
    int wq = __builtin_amdgcn_readfirstlane(threadIdx.x >> 6);  // 0..3, SGPR
    int node0 = blockIdx.x << 6;
    int i = node0 + lane;
    int ic = min(i, n - 1);
    float res[16];
#pragma unroll
    for (int cc = 0; cc < 16; cc++) res[cc] = 0.f;
    const float* Wq = W + wq * 16;               // wave-uniform base
    const float4* xp = (const float4*)(x + (size_t)ic * 32);
#pragma unroll
    for (int q = 0; q < 8; q++)
        accum4<FIN, MODE>(xp[q], Wq + (size_t)(q * 4) * 64, res);
    if (FIN == 96) {
        const float4* hp = (const float4*)(h + (size_t)ic * 64);
#pragma unroll
        for (int q = 0; q < 16; q++)
            accum4<FIN, MODE>(hp[q], Wq + (size_t)(32 + q * 4) * 64, res);
    }
    if (MODE == 1) __syncthreads();   // in-place safety: all reads consumed
    if (i >= n) return;
    if (MODE == 0) {
        float scale = dinv[ic];
        union { unsigned short us[16]; uint4 v[2]; } u;
#pragma unroll
        for (int cc = 0; cc < 16; cc++)
            u.us[cc] = __half_as_ushort(__float2half(res[cc] * scale));
        uint4* dst = (uint4*)((unsigned short*)out + (size_t)i * 64 + wq * 16);
        dst[0] = u.v[0];
        dst[1] = u.v[1];
    } else {
        const float* bp = bias + wq * 16;
        float4* dst = (float4*)((float*)out + (size_t)i * 64 + wq * 16);
#pragma unroll
        for (int t4 = 0; t4 < 4; t4++) {
            float4 o;
            o.x = fmaxf(res[t4 * 4 + 0] + bp[t4 * 4 + 0], 0.f);
            o.y = fmaxf(res[t4 * 4 + 1] + bp[t4 * 4 + 1], 0.f);
            o.z = fmaxf(res[t4 * 4 + 2] + bp[t4 * 4 + 2], 0.f);
            o.w = fmaxf(res[t4 * 4 + 3] + bp[t4 * 4 + 3], 0.f);
            dst[t4] = o;
        }
    }
}

// ---------- pull aggregation over fp16 messages ----------
// 8 lanes/node, 16 B per lane; fp32 accumulate; unroll 4 with four
// independent accumulator sets (4 row-gathers in flight -> hides gather
// latency, the measured limiter). 32 nodes per 256-thread block.
__device__ __forceinline__ void acc8(const uint4 v, float* a) {
    float2 f;
    f = __half22float2(*(const __half2*)&v.x); a[0] += f.x; a[1] += f.y;
    f = __half22float2(*(const __half2*)&v.y); a[2] += f.x; a[3] += f.y;
    f = __half22float2(*(const __half2*)&v.z); a[4] += f.x; a[5] += f.y;
    f = __half22float2(*(const __half2*)&v.w); a[6] += f.x; a[7] += f.y;
}

__global__ __launch_bounds__(256) void aggregate_h(
    const uint4* __restrict__ Tsh4, const int* __restrict__ row_start,
    const int* __restrict__ csr_src, const float* __restrict__ dinv,
    const float* __restrict__ bias, float* __restrict__ hout, int n) {
    int i = blockIdx.x * 32 + (threadIdx.x >> 3);
    if (i >= n) return;
    int q = threadIdx.x & 7;           // channels q*8 .. q*8+7
    float accA[8], accB[8], accC[8], accD[8];
#pragma unroll
    for (int k = 0; k < 8; k++) { accB[k] = 0.f; accC[k] = 0.f; accD[k] = 0.f; }
    {   // self loop (Tsh already * dinv[i])
        uint4 sv = Tsh4[(size_t)i * 8 + q];
        float2 f;
        f = __half22float2(*(const __half2*)&sv.x); accA[0] = f.x; accA[1] = f.y;
        f = __half22float2(*(const __half2*)&sv.y); accA[2] = f.x; accA[3] = f.y;
        f = __half22float2(*(const __half2*)&sv.z); accA[4] = f.x; accA[5] = f.y;
        f = __half22float2(*(const __half2*)&sv.w); accA[6] = f.x; accA[7] = f.y;
    }
    int s0 = row_start[i], s1 = row_start[i + 1];
    int j = s0;
    for (; j + 4 <= s1; j += 4) {
        int sa = csr_src[j], sb = csr_src[j + 1];
        int sc_ = csr_src[j + 2], sd = csr_src[j + 3];
        uint4 va = Tsh4[(size_t)sa * 8 + q];
        uint4 vb = Tsh4[(size_t)sb * 8 + q];
        uint4 vc = Tsh4[(size_t)sc_ * 8 + q];
        uint4 vd = Tsh4[(size_t)sd * 8 + q];
        acc8(va, accA);
        acc8(vb, accB);
        acc8(vc, accC);
        acc8(vd, accD);
    }
    for (; j < s1; j++) {
        int sa = csr_src[j];
        acc8(Tsh4[(size_t)sa * 8 + q], accA);
    }
    float di = dinv[i];
    const float4* bp = (const float4*)(bias + q * 8);
    float4 b0 = bp[0], b1 = bp[1];
    float4 o0, o1;
    o0.x = fmaxf((accA[0] + accB[0] + accC[0] + accD[0]) * di + b0.x, 0.f);
    o0.y = fmaxf((accA[1] + accB[1] + accC[1] + accD[1]) * di + b0.y, 0.f);
    o0.z = fmaxf((accA[2] + accB[2] + accC[2] + accD[2]) * di + b0.z, 0.f);
    o0.w = fmaxf((accA[3] + accB[3] + accC[3] + accD[3]) * di + b0.w, 0.f);
    o1.x = fmaxf((accA[4] + accB[4] + accC[4] + accD[4]) * di + b1.x, 0.f);
    o1.y = fmaxf((accA[5] + accB[5] + accC[5] + accD[5]) * di + b1.y, 0.f);
    o1.z = fmaxf((accA[6] + accB[6] + accC[6] + accD[6]) * di + b1.z, 0.f);
    o1.w = fmaxf((accA[7] + accB[7] + accC[7] + accD[7]) * di + b1.w, 0.f);
    float4* op = (float4*)(hout + (size_t)i * 64 + q * 8);
    op[0] = o0;
    op[1] = o1;
}

// ---------- final head: sigmoid(concat(x,h5) @ Wl2 + bl2) ----------
__global__ __launch_bounds__(256) void final_kernel(
    const float* __restrict__ x, const float* __restrict__ h5,
    const float* __restrict__ Wl2, const float* __restrict__ bl2,
    float* __restrict__ out, int n) {
    int i = blockIdx.x * TPB + threadIdx.x;
    if (i >= n) return;
    float acc = bl2[0];
#pragma unroll
    for (int k = 0; k < 32; k++) acc = fmaf(x[(size_t)i * 32 + k], Wl2[k], acc);
#pragma unroll
    for (int k = 0; k < 64; k++) acc = fmaf(h5[(size_t)i * 64 + k], Wl2[32 + k], acc);
    out[i] = 1.f / (1.f + expf(-acc));
}

extern "C" void kernel_launch(void* const* d_in, const int* in_sizes, int n_in,
                              void* d_out, int out_size, void* d_ws, size_t ws_size,
                              hipStream_t stream) {
    const float* x   = (const float*)d_in[0];
    const int*   edg = (const int*)d_in[1];
    const float* W1  = (const float*)d_in[2];
    const float* b1  = (const float*)d_in[3];
    const float* W2  = (const float*)d_in[4];
    const float* b2  = (const float*)d_in[5];
    const float* W3  = (const float*)d_in[6];
    const float* b3  = (const float*)d_in[7];
    const float* W4  = (const float*)d_in[8];
    const float* b4  = (const float*)d_in[9];
    const float* Wl1 = (const float*)d_in[10];
    const float* bl1 = (const float*)d_in[11];
    const float* Wl2 = (const float*)d_in[12];
    const float* bl2 = (const float*)d_in[13];
    int n = in_sizes[0] / 32;
    int e = in_sizes[1] / 2;
    int B = (n + BNODES - 1) >> BSHIFT;

    char* ws = (char*)d_ws;
    size_t off = 0;
    auto take = [&](size_t bytes) {
        char* p = ws + off;
        off = (off + bytes + 255) & ~(size_t)255;
        return p;
    };
    int*   bucket_cnt    = (int*)take((size_t)B * 4);
    int*   bucket_start  = (int*)take((size_t)(B + 1) * 4);
    int*   bucket_cursor = (int*)take((size_t)B * 4);
    int*   row_start     = (int*)take((size_t)(n + 1) * 4);
    int*   csr_src       = (int*)take((size_t)e * 4);
    float* dinv          = (float*)take((size_t)n * 4);
    unsigned* Tsh        = (unsigned*)take((size_t)n * 64 * 2);  // fp16 messages
    float* hbuf          = (float*)take((size_t)n * 64 * 4);
    unsigned* ebuf = (unsigned*)Tsh;  // alias (e*4 == n*128 here); consumed before gemm1

    hipMemsetAsync(bucket_cnt, 0, (size_t)B * 4, stream);

    int nb = (n + TPB - 1) / TPB;
    int nspans = (e + SPAN - 1) / SPAN;
    hist_kernel<<<512, 256, 0, stream>>>((const int2*)edg, bucket_cnt, e, B);
    bscan_kernel<<<1, 1024, 0, stream>>>(bucket_cnt, bucket_start, bucket_cursor,
                                         row_start, n, e, B);
    bin_kernel<<<nspans, 256, 0, stream>>>((const int2*)edg, bucket_cursor, ebuf, e, B);
    finalize_kernel<<<B, 256, 0, stream>>>(ebuf, bucket_start, row_start, csr_src, dinv, n);

    int gb = (n + 63) / 64;   // gemm blocks: 64 nodes, 256 threads (4 waves x 16 ch)
    int ab = (n + 31) / 32;   // aggregate blocks: 32 nodes each (8 lanes/node)

    gemm_node_k<32, 0><<<gb, TPB, 0, stream>>>(x, nullptr, W1, nullptr, dinv, Tsh, n);
    aggregate_h<<<ab, TPB, 0, stream>>>((const uint4*)Tsh, row_start, csr_src, dinv, b1, hbuf, n);
    gemm_node_k<96, 0><<<gb, TPB, 0, stream>>>(x, hbuf, W2, nullptr, dinv, Tsh, n);
    aggregate_h<<<ab, TPB, 0, stream>>>((const uint4*)Tsh, row_start, csr_src, dinv, b2, hbuf, n);
    gemm_node_k<96, 0><<<gb, TPB, 0, stream>>>(x, hbuf, W3, nullptr, dinv, Tsh, n);
    aggregate_h<<<ab, TPB, 0, stream>>>((const uint4*)Tsh, row_start, csr_src, dinv, b3, hbuf, n);
    gemm_node_k<96, 0><<<gb, TPB, 0, stream>>>(x, hbuf, W4, nullptr, dinv, Tsh, n);
    aggregate_h<<<ab, TPB, 0, stream>>>((const uint4*)Tsh, row_start, csr_src, dinv, b4, hbuf, n);
    // lin1 in-place: hbuf = relu(concat(x,hbuf) @ Wl1 + bl1)
    gemm_node_k<96, 1><<<gb, TPB, 0, stream>>>(x, hbuf, Wl1, bl1, dinv, hbuf, n);
    final_kernel<<<nb, TPB, 0, stream>>>(x, hbuf, Wl2, bl2, (float*)d_out, n);
}